// Round 20
// baseline (1013.173 us; speedup 1.0000x reference)
//
#include <hip/hip_runtime.h>
#include <math.h>

#define OUTW 56
#define ROWS 16
#define NT   256

struct TrigC { double c0,s0,c1,s1,c2,s2,c3,s3; };
struct TrigF { float  c0,s0,c1,s1,c2,s2,c3,s3; };

// ============================================================================
// Kernel A: f32 wave-autonomous column sweep (r14 structure), flags pixels
// whose NMS/bin decisions are within f32-noise of a boundary into a compacted
// list in d_ws. Guards: abs 0.25 / rel 1e-3 on pos/neg (f32 worst-case error
// ~2e-2 -> 12x margin), abs 0.05 / rel 1e-3 on bin tests and |gy|.
// ============================================================================
struct ChSF { float hA,hB,hC,hD, d0,d1, v0,v1, rwP; };

__global__ __launch_bounds__(NT, 2) void canny_wave_f32(
    const float* __restrict__ img, const float* __restrict__ gauss,
    float* __restrict__ out_blur, float* __restrict__ out_mag,
    float* __restrict__ out_ori, float* __restrict__ out_thin,
    float* __restrict__ out_thr, float* __restrict__ out_early,
    unsigned* __restrict__ wcnt, unsigned* __restrict__ wlist, unsigned cap,
    TrigF tc, int H, int W)
{
    const int lane  = threadIdx.x & 63;
    const int wid   = threadIdx.x >> 6;
    const int strip = blockIdx.x;
    const int seg   = blockIdx.y * 4 + wid;
    const int b     = blockIdx.z;

    const int  x   = strip * OUTW + lane - 4;
    const bool xin = (unsigned)x < (unsigned)W;
    const int  r0  = seg * ROWS;

    const float g0 = gauss[0], g1 = gauss[1], g2 = gauss[2];
    const size_t cs = (size_t)H * W;
    const float* ip0 = img + (size_t)(b * 3 + 0) * cs;
    const float* ip1 = ip0 + cs;
    const float* ip2 = ip1 + cs;
    float* bp0 = out_blur + (size_t)(b * 3 + 0) * cs;
    float* bp1 = bp0 + cs;
    float* bp2 = bp1 + cs;

    const bool outok = xin && lane >= 4 && lane <= 59;

    auto rawload = [&](const float* ip, int y) -> float {
        return (xin && (unsigned)y < (unsigned)H) ? ip[(size_t)y * W + x] : 0.f;
    };
    auto hconv = [&](float rw) -> float {
        float m2 = __shfl(rw, lane - 2);
        float m1 = __shfl(rw, lane - 1);
        float p1 = __shfl(rw, lane + 1);
        float p2 = __shfl(rw, lane + 2);
        return g0 * (m2 + p2) + g1 * (m1 + p1) + g2 * rw;
    };
    auto hinit = [&](const float* ip, ChSF& s) {
        s.hA = hconv(rawload(ip, r0 - 4));
        s.hB = hconv(rawload(ip, r0 - 3));
        s.hC = hconv(rawload(ip, r0 - 2));
        s.hD = hconv(rawload(ip, r0 - 1));
        s.d0 = 0.f; s.d1 = 0.f; s.v0 = 0.f; s.v1 = 0.f;
        s.rwP = rawload(ip, r0);
    };
    auto chstep = [&](const float* ip, float* bp, ChSF& s, int v,
                      float& msum, float& gxs, float& gys) {
        float rw = s.rwP;
        s.rwP = rawload(ip, v + 3);
        float hE = hconv(rw);
        float vbn = g0 * (s.hA + hE) + g1 * (s.hB + s.hD) + g2 * s.hC;
        if (!xin || (unsigned)v >= (unsigned)H) vbn = 0.f;
        if (v >= r0 && v < r0 + ROWS && outok)
            bp[(size_t)v * W + x] = vbn;
        float vbL = __shfl(vbn, lane - 1), vbR = __shfl(vbn, lane + 1);
        float dn = vbL - vbR;
        float cc = s.v0 - vbn;
        float cL = __shfl(cc, lane - 1), cR = __shfl(cc, lane + 1);
        float gx = s.d0 + 2.f * s.d1 + dn;
        float gy = cL + 2.f * cc + cR;
        msum += sqrtf(gx * gx + gy * gy);
        gxs += gx; gys += gy;
        s.hA = s.hB; s.hB = s.hC; s.hC = s.hD; s.hD = hE;
        s.d0 = s.d1; s.d1 = dn;
        s.v0 = s.v1; s.v1 = vbn;
    };

    ChSF c0s, c1s, c2s;
    hinit(ip0, c0s); hinit(ip1, c1s); hinit(ip2, c2s);

    float mg0 = 0.f, mg1 = 0.f, mgL0 = 0.f, mgL1 = 0.f, mgR0 = 0.f, mgR1 = 0.f;
    float gxp = 0.f, gyp = 0.f;
    const size_t ob = (size_t)b * cs;

    for (int v = r0 - 2; v <= r0 + ROWS + 1; ++v) {
        float msum = 0.f, gxn = 0.f, gyn = 0.f;
        chstep(ip0, bp0, c0s, v, msum, gxn, gyn);
        chstep(ip1, bp1, c1s, v, msum, gxn, gyn);
        chstep(ip2, bp2, c2s, v, msum, gxn, gyn);
        const int m = v - 1;
        const bool mv = ((unsigned)m < (unsigned)H) && xin && lane >= 3 && lane <= 60;
        float magn = mv ? msum : 0.f;
        float mgLn = __shfl(magn, lane - 1);
        float mgRn = __shfl(magn, lane + 1);

        if (v >= r0 + 2 && outok) {
            const int r = v - 2;
            float m_c = mg1;
            float gxv = gxp, gyv = gyp;

            float a = fabsf(gyv);
            float t0 = a * tc.c0 - gxv * tc.s0;
            float t1 = a * tc.c1 - gxv * tc.s1;
            float t2 = a * tc.c2 - gxv * tc.s2;
            float t3 = a * tc.c3 - gxv * tc.s3;
            int n = (int)(t0 >= 0.f) + (int)(t1 >= 0.f)
                  + (int)(t2 >= 0.f) + (int)(t3 >= 0.f);
            int k;
            if (gyv == 0.f) {
                bool gxneg = signbit(gxv);
                k = signbit(gyv) ? (gxneg ? 0 : 4) : (gxneg ? 8 : 4);
            } else {
                k = signbit(gyv) ? 4 - n : 4 + n;
            }
            float q = 45.f * (float)k;
            if (gxv < 0.f && fabsf(gyv) < 1e-2f) q = 180.f;   // 0/360 hedge

            int kp = k & 7;
            int dy = (int)((0x00012221u >> (kp * 4)) & 7u) - 1;
            int dx = (int)((0x21000122u >> (kp * 4)) & 7u) - 1;

            float rL = (dy < 0) ? mgL0 : (dy > 0 ? mgLn : mgL1);
            float rC = (dy < 0) ? mg0  : (dy > 0 ? magn : mg1);
            float rR = (dy < 0) ? mgR0 : (dy > 0 ? mgRn : mgR1);
            float posn = (dx < 0) ? rL : (dx > 0 ? rR : rC);
            float sL = (dy > 0) ? mgL0 : (dy < 0 ? mgLn : mgL1);
            float sC = (dy > 0) ? mg0  : (dy < 0 ? magn : mg1);
            float sR = (dy > 0) ? mgR0 : (dy < 0 ? mgRn : mgR1);
            float negn = (dx > 0) ? sL : (dx < 0 ? sR : sC);

            float pos = m_c - posn;
            float neg = m_c - negn;
            float thin = (fminf(pos, neg) > 0.f) ? m_c : 0.f;
            size_t idx = ob + (size_t)r * W + x;
            out_mag[idx]   = m_c;
            out_ori[idx]   = q;
            out_thin[idx]  = thin;
            out_thr[idx]   = (thin < 10.f) ? 0.f : thin;
            out_early[idx] = (m_c < 10.f) ? 0.f : m_c;

            // decision-marginal guard -> append for f64 repair
            float gmag = a + fabsf(gxv);
            bool flg = (fabsf(pos) < 0.25f + 1e-3f * (m_c + posn))
                    || (fabsf(neg) < 0.25f + 1e-3f * (m_c + negn))
                    || (a < 0.05f + 1e-3f * fabsf(gxv))
                    || (fabsf(t0) < 0.05f + 1e-3f * gmag)
                    || (fabsf(t1) < 0.05f + 1e-3f * gmag)
                    || (fabsf(t2) < 0.05f + 1e-3f * gmag)
                    || (fabsf(t3) < 0.05f + 1e-3f * gmag);
            if (flg) {
                unsigned id = atomicAdd(wcnt, 1u);
                if (id < cap)
                    wlist[id] = (unsigned)(((unsigned)(b * H + r)) * (unsigned)W + (unsigned)x);
            }
        }

        mg0 = mg1; mg1 = magn;
        mgL0 = mgL1; mgL1 = mgLn;
        mgR0 = mgR1; mgR1 = mgRn;
        gxp = gxn; gyp = gyn;
    }
}

// ============================================================================
// Kernel B: exact-f64 scalar repair of flagged pixels (compacted list).
// Association mirrors the passing r9/r14 f64 chain exactly.
// ============================================================================
__global__ __launch_bounds__(256, 2) void canny_fix_f64(
    const float* __restrict__ img, const float* __restrict__ gauss,
    float* __restrict__ out_mag, float* __restrict__ out_ori,
    float* __restrict__ out_thin, float* __restrict__ out_thr,
    float* __restrict__ out_early,
    const unsigned* __restrict__ ws, unsigned cap, TrigC tc, int H, int W)
{
    unsigned count = ws[0];
    if (count > cap) count = cap;
    const double g0 = (double)gauss[0], g1 = (double)gauss[1], g2 = (double)gauss[2];
    const size_t cs = (size_t)H * W;

    for (unsigned t = blockIdx.x * blockDim.x + threadIdx.x; t < count;
         t += gridDim.x * blockDim.x) {
        unsigned code = ws[1 + t];
        int x = (int)(code % (unsigned)W);
        unsigned rest = code / (unsigned)W;
        int y = (int)(rest % (unsigned)H);
        int b = (int)(rest / (unsigned)H);
        const float* ch0 = img + (size_t)b * 3 * cs;

        auto hline = [&](const float* ip, int yy, int xx) -> double {
            if ((unsigned)yy >= (unsigned)H) return 0.0;
            const float* row = ip + (size_t)yy * W;
            auto rv = [&](int c) -> double {
                return ((unsigned)c < (unsigned)W) ? (double)row[c] : 0.0;
            };
            return g0 * (rv(xx - 2) + rv(xx + 2)) + g1 * (rv(xx - 1) + rv(xx + 1)) + g2 * rv(xx);
        };
        auto vbf = [&](const float* ip, int yy, int xx) -> double {
            if ((unsigned)yy >= (unsigned)H || (unsigned)xx >= (unsigned)W) return 0.0;
            return g0 * (hline(ip, yy - 2, xx) + hline(ip, yy + 2, xx))
                 + g1 * (hline(ip, yy - 1, xx) + hline(ip, yy + 1, xx))
                 + g2 * hline(ip, yy, xx);
        };
        auto sob = [&](const float* ip, int yy, int xx, double& gx, double& gy) {
            double a00 = vbf(ip, yy - 1, xx - 1), a01 = vbf(ip, yy - 1, xx), a02 = vbf(ip, yy - 1, xx + 1);
            double a10 = vbf(ip, yy, xx - 1),                                a12 = vbf(ip, yy, xx + 1);
            double a20 = vbf(ip, yy + 1, xx - 1), a21 = vbf(ip, yy + 1, xx), a22 = vbf(ip, yy + 1, xx + 1);
            gx = (a00 - a02) + 2.0 * (a10 - a12) + (a20 - a22);
            gy = (a00 - a20) + 2.0 * (a01 - a21) + (a02 - a22);
        };
        auto magf = [&](int yy, int xx) -> double {
            if ((unsigned)yy >= (unsigned)H || (unsigned)xx >= (unsigned)W) return 0.0;
            double s = 0.0;
            for (int c = 0; c < 3; ++c) {
                double gx, gy; sob(ch0 + (size_t)c * cs, yy, xx, gx, gy);
                s += sqrt(gx * gx + gy * gy);
            }
            return s;
        };

        double gxs = 0.0, gys = 0.0;
        for (int c = 0; c < 3; ++c) {
            double gx, gy; sob(ch0 + (size_t)c * cs, y, x, gx, gy);
            gxs += gx; gys += gy;
        }
        double m_c = magf(y, x);

        double a = fabs(gys);
        int n = (int)(a * tc.c0 - gxs * tc.s0 >= 0.0)
              + (int)(a * tc.c1 - gxs * tc.s1 >= 0.0)
              + (int)(a * tc.c2 - gxs * tc.s2 >= 0.0)
              + (int)(a * tc.c3 - gxs * tc.s3 >= 0.0);
        int k;
        if (gys == 0.0) {
            bool gxneg = signbit(gxs);
            k = signbit(gys) ? (gxneg ? 0 : 4) : (gxneg ? 8 : 4);
        } else {
            k = signbit(gys) ? 4 - n : 4 + n;
        }
        float q = 45.f * (float)k;
        if (gxs < 0.0 && fabs(gys) < 1e-2) q = 180.f;

        int kp = k & 7;
        int dy = (int)((0x00012221u >> (kp * 4)) & 7u) - 1;
        int dx = (int)((0x21000122u >> (kp * 4)) & 7u) - 1;
        double pos = m_c - magf(y + dy, x + dx);
        double neg = m_c - magf(y - dy, x - dx);
        float mf = (float)m_c;
        float thin = (fmin(pos, neg) > 0.0) ? mf : 0.f;

        size_t idx = (size_t)b * cs + (size_t)y * W + x;
        out_mag[idx]   = mf;
        out_ori[idx]   = q;
        out_thin[idx]  = thin;
        out_thr[idx]   = (thin < 10.f) ? 0.f : thin;
        out_early[idx] = (mf < 10.f) ? 0.f : mf;
    }
}

__global__ void canny_zero_cnt(unsigned* c) { if (threadIdx.x == 0) c[0] = 0u; }

// ============================================================================
// Fallback: proven f64 wave sweep (r14, 80.5us) if ws is too small.
// ============================================================================
struct ChS64 { double hA,hB,hC,hD, d0,d1, v0,v1; float rwP; };

__global__ __launch_bounds__(NT, 2) void canny_wave_f64(
    const float* __restrict__ img, const float* __restrict__ gauss,
    float* __restrict__ out_blur, float* __restrict__ out_mag,
    float* __restrict__ out_ori, float* __restrict__ out_thin,
    float* __restrict__ out_thr, float* __restrict__ out_early,
    TrigC tc, int H, int W)
{
    const int lane  = threadIdx.x & 63;
    const int wid   = threadIdx.x >> 6;
    const int strip = blockIdx.x;
    const int seg   = blockIdx.y * 4 + wid;
    const int b     = blockIdx.z;
    const int  x   = strip * OUTW + lane - 4;
    const bool xin = (unsigned)x < (unsigned)W;
    const int  r0  = seg * ROWS;
    const double g0 = (double)gauss[0], g1 = (double)gauss[1], g2 = (double)gauss[2];
    const size_t cs = (size_t)H * W;
    const float* ip0 = img + (size_t)(b * 3 + 0) * cs;
    const float* ip1 = ip0 + cs;
    const float* ip2 = ip1 + cs;
    float* bp0 = out_blur + (size_t)(b * 3 + 0) * cs;
    float* bp1 = bp0 + cs;
    float* bp2 = bp1 + cs;
    const bool outok = xin && lane >= 4 && lane <= 59;

    auto rawload = [&](const float* ip, int y) -> float {
        return (xin && (unsigned)y < (unsigned)H) ? ip[(size_t)y * W + x] : 0.f;
    };
    auto hconv = [&](float rw) -> double {
        float m2 = __shfl(rw, lane - 2);
        float m1 = __shfl(rw, lane - 1);
        float p1 = __shfl(rw, lane + 1);
        float p2 = __shfl(rw, lane + 2);
        return g0 * ((double)m2 + (double)p2) + g1 * ((double)m1 + (double)p1) + g2 * (double)rw;
    };
    auto hinit = [&](const float* ip, ChS64& s) {
        s.hA = hconv(rawload(ip, r0 - 4));
        s.hB = hconv(rawload(ip, r0 - 3));
        s.hC = hconv(rawload(ip, r0 - 2));
        s.hD = hconv(rawload(ip, r0 - 1));
        s.d0 = 0.0; s.d1 = 0.0; s.v0 = 0.0; s.v1 = 0.0;
        s.rwP = rawload(ip, r0);
    };
    auto chstep = [&](const float* ip, float* bp, ChS64& s, int v,
                      double& msum, double& gxs, double& gys) {
        float rw = s.rwP;
        s.rwP = rawload(ip, v + 3);
        double hE = hconv(rw);
        double vbn = g0 * (s.hA + hE) + g1 * (s.hB + s.hD) + g2 * s.hC;
        if (!xin || (unsigned)v >= (unsigned)H) vbn = 0.0;
        if (v >= r0 && v < r0 + ROWS && outok)
            bp[(size_t)v * W + x] = (float)vbn;
        double vbL = __shfl(vbn, lane - 1), vbR = __shfl(vbn, lane + 1);
        double dn = vbL - vbR;
        double cc = s.v0 - vbn;
        double cL = __shfl(cc, lane - 1), cR = __shfl(cc, lane + 1);
        double gx = s.d0 + 2.0 * s.d1 + dn;
        double gy = cL + 2.0 * cc + cR;
        msum += sqrt(gx * gx + gy * gy);
        gxs += gx; gys += gy;
        s.hA = s.hB; s.hB = s.hC; s.hC = s.hD; s.hD = hE;
        s.d0 = s.d1; s.d1 = dn;
        s.v0 = s.v1; s.v1 = vbn;
    };

    ChS64 c0s, c1s, c2s;
    hinit(ip0, c0s); hinit(ip1, c1s); hinit(ip2, c2s);
    double mg0 = 0.0, mg1 = 0.0, mgL0 = 0.0, mgL1 = 0.0, mgR0 = 0.0, mgR1 = 0.0;
    double gxp = 0.0, gyp = 0.0;
    const size_t ob = (size_t)b * cs;

    for (int v = r0 - 2; v <= r0 + ROWS + 1; ++v) {
        double msum = 0.0, gxn = 0.0, gyn = 0.0;
        chstep(ip0, bp0, c0s, v, msum, gxn, gyn);
        chstep(ip1, bp1, c1s, v, msum, gxn, gyn);
        chstep(ip2, bp2, c2s, v, msum, gxn, gyn);
        const int m = v - 1;
        const bool mv = ((unsigned)m < (unsigned)H) && xin && lane >= 3 && lane <= 60;
        double magn = mv ? msum : 0.0;
        double mgLn = __shfl(magn, lane - 1);
        double mgRn = __shfl(magn, lane + 1);

        if (v >= r0 + 2 && outok) {
            const int r = v - 2;
            double m_c = mg1;
            double gxv = gxp, gyv = gyp;
            double a = fabs(gyv);
            int n = (int)(a * tc.c0 - gxv * tc.s0 >= 0.0)
                  + (int)(a * tc.c1 - gxv * tc.s1 >= 0.0)
                  + (int)(a * tc.c2 - gxv * tc.s2 >= 0.0)
                  + (int)(a * tc.c3 - gxv * tc.s3 >= 0.0);
            int k;
            if (gyv == 0.0) {
                bool gxneg = signbit(gxv);
                k = signbit(gyv) ? (gxneg ? 0 : 4) : (gxneg ? 8 : 4);
            } else {
                k = signbit(gyv) ? 4 - n : 4 + n;
            }
            float q = 45.f * (float)k;
            if (gxv < 0.0 && fabs(gyv) < 1e-2) q = 180.f;
            int kp = k & 7;
            int dy = (int)((0x00012221u >> (kp * 4)) & 7u) - 1;
            int dx = (int)((0x21000122u >> (kp * 4)) & 7u) - 1;
            double rL = (dy < 0) ? mgL0 : (dy > 0 ? mgLn : mgL1);
            double rC = (dy < 0) ? mg0  : (dy > 0 ? magn : mg1);
            double rR = (dy < 0) ? mgR0 : (dy > 0 ? mgRn : mgR1);
            double posn = (dx < 0) ? rL : (dx > 0 ? rR : rC);
            double sL = (dy > 0) ? mgL0 : (dy < 0 ? mgLn : mgL1);
            double sC = (dy > 0) ? mg0  : (dy < 0 ? magn : mg1);
            double sR = (dy > 0) ? mgR0 : (dy < 0 ? mgRn : mgR1);
            double negn = (dx > 0) ? sL : (dx < 0 ? sR : sC);
            double pos = m_c - posn;
            double neg = m_c - negn;
            float mf = (float)m_c;
            float thin = (fmin(pos, neg) > 0.0) ? mf : 0.f;
            size_t idx = ob + (size_t)r * W + x;
            out_mag[idx]   = mf;
            out_ori[idx]   = q;
            out_thin[idx]  = thin;
            out_thr[idx]   = (thin < 10.f) ? 0.f : thin;
            out_early[idx] = (mf < 10.f) ? 0.f : mf;
        }
        mg0 = mg1; mg1 = magn;
        mgL0 = mgL1; mgL1 = mgLn;
        mgR0 = mgR1; mgR1 = mgRn;
        gxp = gxn; gyp = gyn;
    }
}

extern "C" void kernel_launch(void* const* d_in, const int* in_sizes, int n_in,
                              void* d_out, int out_size, void* d_ws, size_t ws_size,
                              hipStream_t stream) {
    const float* img   = (const float*)d_in[0];
    const float* gauss = (const float*)d_in[1];
    const int H = 1024, W = 1024;
    const int B = in_sizes[0] / (3 * H * W);

    float* out = (float*)d_out;
    const size_t cs = (size_t)H * W;
    float* out_blur  = out;
    float* out_mag   = out_blur + (size_t)B * 3 * cs;
    float* out_ori   = out_mag  + (size_t)B * cs;
    float* out_thin  = out_ori  + (size_t)B * cs;
    float* out_thr   = out_thin + (size_t)B * cs;
    float* out_early = out_thr  + (size_t)B * cs;

    const double C = 180.0 / 3.14159;
    TrigC tc;
    { double bta = 22.5 / C;  tc.c0 = cos(bta); tc.s0 = sin(bta); }
    { double bta = 67.5 / C;  tc.c1 = cos(bta); tc.s1 = sin(bta); }
    { double bta = 112.5 / C; tc.c2 = cos(bta); tc.s2 = sin(bta); }
    { double bta = 157.5 / C; tc.c3 = cos(bta); tc.s3 = sin(bta); }

    dim3 grid((W + OUTW - 1) / OUTW, H / (ROWS * 4), B);

    if (ws_size < (1u << 20) || d_ws == nullptr) {
        // not enough scratch for the repair list: proven f64 path
        canny_wave_f64<<<grid, NT, 0, stream>>>(
            img, gauss, out_blur, out_mag, out_ori, out_thin, out_thr, out_early,
            tc, H, W);
        return;
    }

    TrigF tf = { (float)tc.c0, (float)tc.s0, (float)tc.c1, (float)tc.s1,
                 (float)tc.c2, (float)tc.s2, (float)tc.c3, (float)tc.s3 };
    unsigned* wcnt  = (unsigned*)d_ws;
    unsigned* wlist = wcnt + 1;
    size_t cap_sz = (ws_size - 4) / 4;
    unsigned cap = (cap_sz > (1u << 26)) ? (1u << 26) : (unsigned)cap_sz;

    canny_zero_cnt<<<1, 64, 0, stream>>>(wcnt);
    canny_wave_f32<<<grid, NT, 0, stream>>>(
        img, gauss, out_blur, out_mag, out_ori, out_thin, out_thr, out_early,
        wcnt, wlist, cap, tf, H, W);
    canny_fix_f64<<<512, 256, 0, stream>>>(
        img, gauss, out_mag, out_ori, out_thin, out_thr, out_early,
        (const unsigned*)d_ws, cap, tc, H, W);
}